// Round 1
// baseline (591.635 us; speedup 1.0000x reference)
//
#include <hip/hip_runtime.h>

#define AS1 __attribute__((address_space(1)))
#define AS3 __attribute__((address_space(3)))

typedef __attribute__((ext_vector_type(8))) __bf16 bf16x8;
typedef __attribute__((ext_vector_type(4))) float f32x4;

static constexpr int N  = 8192;
static constexpr int P  = 128;
static constexpr int D  = 256;
static constexpr int KC = 384;   // P + D concatenated K

__device__ __forceinline__ unsigned short f32_bf16(float f) {
  union { float f; unsigned u; } v; v.f = f;
  unsigned r = v.u + 0x7fffu + ((v.u >> 16) & 1u);   // round-to-nearest-even
  return (unsigned short)(r >> 16);
}

__device__ __forceinline__ void glds16(const void* g, void* l) {
  __builtin_amdgcn_global_load_lds((const AS1 void*)g, (AS3 void*)l, 16, 0, 0);
}

// ---------- P1: row-normalize embeddings -> xn into a_cat, -xn into b_cat ----------
__global__ __launch_bounds__(256)
void prep_xn_kernel(const float* __restrict__ emb,
                    unsigned short* __restrict__ a_cat,
                    unsigned short* __restrict__ b_cat) {
  const int i = blockIdx.x;
  const int j = threadIdx.x;            // D == 256 == blockDim
  float x = emb[(size_t)i * D + j];
  float ss = x * x;
  #pragma unroll
  for (int o = 32; o > 0; o >>= 1) ss += __shfl_down(ss, o, 64);
  __shared__ float red[4];
  if ((threadIdx.x & 63) == 0) red[threadIdx.x >> 6] = ss;
  __syncthreads();
  float tot = red[0] + red[1] + red[2] + red[3];
  float inv = 1.0f / fmaxf(sqrtf(tot), 1e-8f);
  float xn = x * inv;
  a_cat[(size_t)i * KC + P + j] = f32_bf16(xn);
  b_cat[(size_t)i * KC + P + j] = f32_bf16(-xn);
}

// ---------- P2: cast Pred -> cat arrays + LDS-tiled transpose predT + weight loss ----------
__global__ __launch_bounds__(256)
void prep_pred_kernel(const float* __restrict__ pred,
                      const float* __restrict__ wts,
                      unsigned short* __restrict__ a_cat,
                      unsigned short* __restrict__ b_cat,
                      unsigned short* __restrict__ predT,
                      float* __restrict__ wtp) {
  __shared__ unsigned short t[P][72];   // 64 i-cols + pad
  const int tid = threadIdx.x;
  const int i0 = blockIdx.x * 64;
  float s = 0.f;
  #pragma unroll
  for (int k = 0; k < 32; ++k) {
    int e = k * 256 + tid;              // 0..8191 over 64x128 tile
    int ii = e >> 7, p = e & 127;
    size_t idx = (size_t)(i0 + ii) * P + p;
    float v = pred[idx];
    unsigned short h = f32_bf16(v);
    a_cat[(size_t)(i0 + ii) * KC + p] = h;
    b_cat[(size_t)(i0 + ii) * KC + p] = h;
    t[p][ii] = h;
    float d = v - wts[idx];
    s += d * d;
  }
  __syncthreads();
  #pragma unroll
  for (int k = 0; k < 32; ++k) {
    int e = k * 256 + tid;
    int p = e >> 6, ii = e & 63;
    predT[(size_t)p * N + i0 + ii] = t[p][ii];   // coalesced 128B runs
  }
  #pragma unroll
  for (int o = 32; o > 0; o >>= 1) s += __shfl_down(s, o, 64);
  __shared__ float red[4];
  if ((tid & 63) == 0) red[tid >> 6] = s;
  __syncthreads();
  if (tid == 0) wtp[blockIdx.x] = red[0] + red[1] + red[2] + red[3];
}

// ---------- coherence: sum over (a_cat . b_cat^T)^2, symmetric tiles only ----------
__global__ __launch_bounds__(256)
void coherence_kernel(const unsigned short* __restrict__ A,
                      const unsigned short* __restrict__ B,
                      float* __restrict__ cohp) {
  const int bi = blockIdx.x, bj = blockIdx.y;
  const int cid = bj * 64 + bi;
  const int tid = threadIdx.x;
  if (bi > bj) { if (tid == 0) cohp[cid] = 0.f; return; }   // symmetry: skip lower tiles
  __shared__ unsigned short As[128 * 32];
  __shared__ unsigned short Bs[128 * 32];
  const int w = tid >> 6, lane = tid & 63;
  const int wr = (w >> 1) * 64, wc = (w & 1) * 64;
  const int ml = lane & 15, kq = (lane >> 4) * 8;
  f32x4 acc[4][4] = {};
  const size_t abase = (size_t)bi * 128 * KC;
  const size_t bbase = (size_t)bj * 128 * KC;
  for (int k0 = 0; k0 < KC; k0 += 32) {
    __syncthreads();
    #pragma unroll
    for (int p = 0; p < 2; ++p) {
      int e = p * 2048 + tid * 8;
      int row = e >> 5, col = e & 31;
      glds16(A + abase + (size_t)row * KC + k0 + col, &As[e]);
      glds16(B + bbase + (size_t)row * KC + k0 + col, &Bs[e]);
    }
    __syncthreads();
    bf16x8 af[4], bf[4];
    #pragma unroll
    for (int i = 0; i < 4; ++i) {
      af[i] = *(const bf16x8*)&As[(wr + i * 16 + ml) * 32 + kq];
      bf[i] = *(const bf16x8*)&Bs[(wc + i * 16 + ml) * 32 + kq];
    }
    #pragma unroll
    for (int i = 0; i < 4; ++i)
      #pragma unroll
      for (int j = 0; j < 4; ++j)
        acc[i][j] = __builtin_amdgcn_mfma_f32_16x16x32_bf16(af[i], bf[j], acc[i][j], 0, 0, 0);
  }
  float s = 0.f;
  #pragma unroll
  for (int i = 0; i < 4; ++i)
    #pragma unroll
    for (int j = 0; j < 4; ++j)
      #pragma unroll
      for (int e = 0; e < 4; ++e) { float c = acc[i][j][e]; s += c * c; }
  if (bi != bj) s *= 2.f;               // mirrored tile
  #pragma unroll
  for (int o = 32; o > 0; o >>= 1) s += __shfl_down(s, o, 64);
  __shared__ float red[4];
  if (lane == 0) red[w] = s;
  __syncthreads();
  if (tid == 0) cohp[cid] = red[0] + red[1] + red[2] + red[3];
}

// ---------- structure: fused (Pred - Adj.Pred)^2, Adj fp32->bf16 in-kernel ----------
__global__ __launch_bounds__(256)
void structure_kernel(const float* __restrict__ adj,
                      const unsigned short* __restrict__ predT,
                      const float* __restrict__ pred,
                      float* __restrict__ strp) {
  __shared__ unsigned short As[2][16 * 32];    // adj tile, double-buffered
  __shared__ unsigned short Bs[2][128 * 32];   // predT tile, double-buffered
  const int tid = threadIdx.x;
  const int r0 = blockIdx.x * 16;
  const int w = tid >> 6, lane = tid & 63;
  const int wc = w * 32;
  const int ml = lane & 15, kq = (lane >> 4) * 8;
  const int arow = tid >> 4, acol = (tid & 15) * 2;
  const float* aptr = adj + (size_t)(r0 + arow) * N + acol;
  f32x4 acc0 = {0.f, 0.f, 0.f, 0.f}, acc1 = {0.f, 0.f, 0.f, 0.f};

  // prologue: stage tile 0
  float2 av = *(const float2*)aptr;
  #pragma unroll
  for (int p = 0; p < 2; ++p) {
    int e = p * 2048 + tid * 8;
    int prow = e >> 5, pcol = e & 31;
    glds16(predT + (size_t)prow * N + pcol, &Bs[0][e]);
  }
  {
    unsigned pk = (unsigned)f32_bf16(av.x) | ((unsigned)f32_bf16(av.y) << 16);
    *(unsigned*)&As[0][arow * 32 + acol] = pk;
  }
  __syncthreads();

  for (int ks = 0; ks < 256; ++ks) {
    const int buf = ks & 1, nbuf = buf ^ 1;
    const int k1 = (ks + 1) * 32;
    if (ks < 255) {
      av = *(const float2*)(aptr + k1);                  // reg prefetch (HBM)
      #pragma unroll
      for (int p = 0; p < 2; ++p) {
        int e = p * 2048 + tid * 8;
        int prow = e >> 5, pcol = e & 31;
        glds16(predT + (size_t)prow * N + k1 + pcol, &Bs[nbuf][e]);
      }
    }
    bf16x8 a  = *(const bf16x8*)&As[buf][ml * 32 + kq];
    bf16x8 b0 = *(const bf16x8*)&Bs[buf][(wc      + ml) * 32 + kq];
    bf16x8 b1 = *(const bf16x8*)&Bs[buf][(wc + 16 + ml) * 32 + kq];
    acc0 = __builtin_amdgcn_mfma_f32_16x16x32_bf16(a, b0, acc0, 0, 0, 0);
    acc1 = __builtin_amdgcn_mfma_f32_16x16x32_bf16(a, b1, acc1, 0, 0, 0);
    if (ks < 255) {
      unsigned pk = (unsigned)f32_bf16(av.x) | ((unsigned)f32_bf16(av.y) << 16);
      *(unsigned*)&As[nbuf][arow * 32 + acol] = pk;
    }
    __syncthreads();
  }

  // epilogue: C/D layout col=lane&15, row=(lane>>4)*4+reg  [m89/m91]
  float s = 0.f;
  const int rb = r0 + (lane >> 4) * 4;
  const int c0 = wc + ml, c1 = wc + 16 + ml;
  #pragma unroll
  for (int e = 0; e < 4; ++e) {
    float d0 = pred[(size_t)(rb + e) * P + c0] - acc0[e];
    float d1 = pred[(size_t)(rb + e) * P + c1] - acc1[e];
    s += d0 * d0 + d1 * d1;
  }
  #pragma unroll
  for (int o = 32; o > 0; o >>= 1) s += __shfl_down(s, o, 64);
  __shared__ float red[4];
  if (lane == 0) red[w] = s;
  __syncthreads();
  if (tid == 0) strp[blockIdx.x] = red[0] + red[1] + red[2] + red[3];
}

// ---------- final: fp64 reduce of partials, combine losses ----------
__global__ __launch_bounds__(256)
void finalize_kernel(const float* __restrict__ cohp,
                     const float* __restrict__ wtp,
                     const float* __restrict__ strp,
                     float* __restrict__ out) {
  const int tid = threadIdx.x;
  double sc = 0, sw = 0, ss = 0;
  for (int i = tid; i < 4096; i += 256) sc += (double)cohp[i];
  for (int i = tid; i < 128;  i += 256) sw += (double)wtp[i];
  for (int i = tid; i < 512;  i += 256) ss += (double)strp[i];
  #pragma unroll
  for (int o = 32; o > 0; o >>= 1) {
    sc += __shfl_down(sc, o, 64);
    sw += __shfl_down(sw, o, 64);
    ss += __shfl_down(ss, o, 64);
  }
  __shared__ double rd[3][4];
  const int w = tid >> 6, lane = tid & 63;
  if (lane == 0) { rd[0][w] = sc; rd[1][w] = sw; rd[2][w] = ss; }
  __syncthreads();
  if (tid == 0) {
    double c  = rd[0][0] + rd[0][1] + rd[0][2] + rd[0][3];
    double wv = rd[1][0] + rd[1][1] + rd[1][2] + rd[1][3];
    double st = rd[2][0] + rd[2][1] + rd[2][2] + rd[2][3];
    out[0] = (float)(c / ((double)N * (double)N) +
                     st / ((double)N * (double)P) +
                     wv / ((double)N * (double)P));
  }
}

extern "C" void kernel_launch(void* const* d_in, const int* in_sizes, int n_in,
                              void* d_out, int out_size, void* d_ws, size_t ws_size,
                              hipStream_t stream) {
  const float* pred = (const float*)d_in[0];   // [8192,128]
  const float* emb  = (const float*)d_in[1];   // [8192,256]
  const float* adj  = (const float*)d_in[2];   // [8192,8192]
  const float* wts  = (const float*)d_in[3];   // [8192,128]
  float* out = (float*)d_out;
  char* ws = (char*)d_ws;
  // ws layout (needs ~14.7 MB):
  unsigned short* a_cat = (unsigned short*)ws;               // [8192,384] bf16 = 6291456 B
  unsigned short* b_cat = (unsigned short*)(ws + 6291456);   // [8192,384] bf16
  unsigned short* predT = (unsigned short*)(ws + 12582912);  // [128,8192] bf16 = 2097152 B
  float* cohp = (float*)(ws + 14680064);                     // 4096
  float* wtp  = cohp + 4096;                                 // 128
  float* strp = wtp + 128;                                   // 512

  prep_xn_kernel  <<<N,       256, 0, stream>>>(emb, a_cat, b_cat);
  prep_pred_kernel<<<N / 64,  256, 0, stream>>>(pred, wts, a_cat, b_cat, predT, wtp);
  dim3 cg(64, 64);
  coherence_kernel<<<cg,      256, 0, stream>>>(a_cat, b_cat, cohp);
  structure_kernel<<<N / 16,  256, 0, stream>>>(adj, predT, pred, strp);
  finalize_kernel <<<1,       256, 0, stream>>>(cohp, wtp, strp, out);
}

// Round 2
// 541.223 us; speedup vs baseline: 1.0931x; 1.0931x over previous
//
#include <hip/hip_runtime.h>

#define AS1 __attribute__((address_space(1)))
#define AS3 __attribute__((address_space(3)))

typedef __attribute__((ext_vector_type(8))) __bf16 bf16x8;
typedef __attribute__((ext_vector_type(4))) float f32x4;

static constexpr int N  = 8192;
static constexpr int P  = 128;
static constexpr int D  = 256;
static constexpr int KC = 384;   // P + D concatenated K

__device__ __forceinline__ unsigned short f32_bf16(float f) {
  union { float f; unsigned u; } v; v.f = f;
  unsigned r = v.u + 0x7fffu + ((v.u >> 16) & 1u);   // round-to-nearest-even
  return (unsigned short)(r >> 16);
}

__device__ __forceinline__ void glds16(const void* g, void* l) {
  __builtin_amdgcn_global_load_lds((const AS1 void*)g, (AS3 void*)l, 16, 0, 0);
}

// ---------- P1: row-normalize embeddings -> xn into a_cat, -xn into b_cat ----------
__global__ __launch_bounds__(256)
void prep_xn_kernel(const float* __restrict__ emb,
                    unsigned short* __restrict__ a_cat,
                    unsigned short* __restrict__ b_cat) {
  const int i = blockIdx.x;
  const int j = threadIdx.x;            // D == 256 == blockDim
  float x = emb[(size_t)i * D + j];
  float ss = x * x;
  #pragma unroll
  for (int o = 32; o > 0; o >>= 1) ss += __shfl_down(ss, o, 64);
  __shared__ float red[4];
  if ((threadIdx.x & 63) == 0) red[threadIdx.x >> 6] = ss;
  __syncthreads();
  float tot = red[0] + red[1] + red[2] + red[3];
  float inv = 1.0f / fmaxf(sqrtf(tot), 1e-8f);
  float xn = x * inv;
  a_cat[(size_t)i * KC + P + j] = f32_bf16(xn);
  b_cat[(size_t)i * KC + P + j] = f32_bf16(-xn);
}

// ---------- P2: cast Pred -> cat arrays + LDS-tiled transpose predT + weight loss ----------
__global__ __launch_bounds__(256)
void prep_pred_kernel(const float* __restrict__ pred,
                      const float* __restrict__ wts,
                      unsigned short* __restrict__ a_cat,
                      unsigned short* __restrict__ b_cat,
                      unsigned short* __restrict__ predT,
                      float* __restrict__ wtp) {
  __shared__ unsigned short t[P][72];   // 64 i-cols + pad
  const int tid = threadIdx.x;
  const int i0 = blockIdx.x * 64;
  float s = 0.f;
  #pragma unroll
  for (int k = 0; k < 32; ++k) {
    int e = k * 256 + tid;              // 0..8191 over 64x128 tile
    int ii = e >> 7, p = e & 127;
    size_t idx = (size_t)(i0 + ii) * P + p;
    float v = pred[idx];
    unsigned short h = f32_bf16(v);
    a_cat[(size_t)(i0 + ii) * KC + p] = h;
    b_cat[(size_t)(i0 + ii) * KC + p] = h;
    t[p][ii] = h;
    float d = v - wts[idx];
    s += d * d;
  }
  __syncthreads();
  #pragma unroll
  for (int k = 0; k < 32; ++k) {
    int e = k * 256 + tid;
    int p = e >> 6, ii = e & 63;
    predT[(size_t)p * N + i0 + ii] = t[p][ii];   // coalesced 128B runs
  }
  #pragma unroll
  for (int o = 32; o > 0; o >>= 1) s += __shfl_down(s, o, 64);
  __shared__ float red[4];
  if ((tid & 63) == 0) red[tid >> 6] = s;
  __syncthreads();
  if (tid == 0) wtp[blockIdx.x] = red[0] + red[1] + red[2] + red[3];
}

// ---------- coherence: sum over (a_cat . b_cat^T)^2, triangular-packed grid ----------
__global__ __launch_bounds__(256)
void coherence_kernel(const unsigned short* __restrict__ A,
                      const unsigned short* __restrict__ B,
                      float* __restrict__ cohp) {
  const int t = blockIdx.x;             // 0..2079 upper-triangle tiles
  int bj = (int)((sqrtf(8.0f * (float)t + 1.0f) - 1.0f) * 0.5f);
  while ((bj + 1) * (bj + 2) / 2 <= t) ++bj;
  while (bj * (bj + 1) / 2 > t) --bj;
  const int bi = t - bj * (bj + 1) / 2;   // bi <= bj
  const int tid = threadIdx.x;
  __shared__ unsigned short As[128 * 32];
  __shared__ unsigned short Bs[128 * 32];
  const int w = tid >> 6, lane = tid & 63;
  const int wr = (w >> 1) * 64, wc = (w & 1) * 64;
  const int ml = lane & 15, kq = (lane >> 4) * 8;
  f32x4 acc[4][4] = {};
  const size_t abase = (size_t)bi * 128 * KC;
  const size_t bbase = (size_t)bj * 128 * KC;
  for (int k0 = 0; k0 < KC; k0 += 32) {
    __syncthreads();
    #pragma unroll
    for (int p = 0; p < 2; ++p) {
      int e = p * 2048 + tid * 8;
      int row = e >> 5, col = e & 31;
      glds16(A + abase + (size_t)row * KC + k0 + col, &As[e]);
      glds16(B + bbase + (size_t)row * KC + k0 + col, &Bs[e]);
    }
    __syncthreads();
    bf16x8 af[4], bf[4];
    #pragma unroll
    for (int i = 0; i < 4; ++i) {
      af[i] = *(const bf16x8*)&As[(wr + i * 16 + ml) * 32 + kq];
      bf[i] = *(const bf16x8*)&Bs[(wc + i * 16 + ml) * 32 + kq];
    }
    #pragma unroll
    for (int i = 0; i < 4; ++i)
      #pragma unroll
      for (int j = 0; j < 4; ++j)
        acc[i][j] = __builtin_amdgcn_mfma_f32_16x16x32_bf16(af[i], bf[j], acc[i][j], 0, 0, 0);
  }
  float s = 0.f;
  #pragma unroll
  for (int i = 0; i < 4; ++i)
    #pragma unroll
    for (int j = 0; j < 4; ++j)
      #pragma unroll
      for (int e = 0; e < 4; ++e) { float c = acc[i][j][e]; s += c * c; }
  if (bi != bj) s *= 2.f;               // mirrored tile
  #pragma unroll
  for (int o = 32; o > 0; o >>= 1) s += __shfl_down(s, o, 64);
  __shared__ float red[4];
  if (lane == 0) red[w] = s;
  __syncthreads();
  if (tid == 0) cohp[t] = red[0] + red[1] + red[2] + red[3];
}

// ---------- structure GEMM: barrier-free register-direct MFMA, split-K x8 ----------
// A-frag loaded straight from adj (fp32->bf16 in regs), B-frag straight from predT (L2).
__global__ __launch_bounds__(256, 4)
void structure_mfma_kernel(const float* __restrict__ adj,
                           const unsigned short* __restrict__ predT,
                           unsigned short* __restrict__ cpart) {
  const int tid = threadIdx.x;
  const int w = tid >> 6, lane = tid & 63;
  const int ml = lane & 15, kq = (lane >> 4) * 8;
  const int row0 = blockIdx.x * 64 + w * 16;     // wave-private 16 rows
  const int kbeg = blockIdx.y * 1024;            // K-slice
  const float* aptr = adj + (size_t)(row0 + ml) * N + kbeg + kq;
  const unsigned short* bptr = predT + (size_t)ml * N + kbeg + kq;
  f32x4 acc[8] = {};
  float4 a0 = *(const float4*)aptr;
  float4 a1 = *(const float4*)(aptr + 4);
  for (int it = 0; it < 32; ++it) {
    float4 n0 = a0, n1 = a1;
    if (it < 31) {                               // reg prefetch next 32-k chunk (HBM)
      n0 = *(const float4*)(aptr + 32);
      n1 = *(const float4*)(aptr + 36);
    }
    union { bf16x8 v; unsigned short s[8]; } ah;
    ah.s[0] = f32_bf16(a0.x); ah.s[1] = f32_bf16(a0.y);
    ah.s[2] = f32_bf16(a0.z); ah.s[3] = f32_bf16(a0.w);
    ah.s[4] = f32_bf16(a1.x); ah.s[5] = f32_bf16(a1.y);
    ah.s[6] = f32_bf16(a1.z); ah.s[7] = f32_bf16(a1.w);
    #pragma unroll
    for (int f = 0; f < 8; ++f) {
      bf16x8 bf = *(const bf16x8*)(bptr + (size_t)f * 16 * N);  // L2-resident
      acc[f] = __builtin_amdgcn_mfma_f32_16x16x32_bf16(ah.v, bf, acc[f], 0, 0, 0);
    }
    a0 = n0; a1 = n1;
    aptr += 32; bptr += 32;
  }
  // C/D layout: col = lane&15, row = (lane>>4)*4 + e  [m89/m91]
  const int rb = (lane >> 4) * 4;
  unsigned short* cp = cpart + (size_t)blockIdx.y * ((size_t)N * P);
  #pragma unroll
  for (int f = 0; f < 8; ++f)
    #pragma unroll
    for (int e = 0; e < 4; ++e)
      cp[(size_t)(row0 + rb + e) * P + f * 16 + ml] = f32_bf16(acc[f][e]);
}

// ---------- structure reduce: sum 8 bf16 partial slices, (pred - C)^2 ----------
__global__ __launch_bounds__(256)
void structure_reduce_kernel(const unsigned short* __restrict__ cpart,
                             const float* __restrict__ pred,
                             float* __restrict__ strp) {
  const int tid = threadIdx.x;
  const size_t base = ((size_t)blockIdx.x * 256 + tid) * 8;
  const float4 p0 = *(const float4*)(pred + base);
  const float4 p1 = *(const float4*)(pred + base + 4);
  float c[8] = {};
  #pragma unroll
  for (int sl = 0; sl < 8; ++sl) {
    union { bf16x8 v; unsigned short u[8]; } t;
    t.v = *(const bf16x8*)(cpart + (size_t)sl * ((size_t)N * P) + base);
    #pragma unroll
    for (int e = 0; e < 8; ++e) {
      union { unsigned u; float f; } cv; cv.u = ((unsigned)t.u[e]) << 16;
      c[e] += cv.f;
    }
  }
  const float pv[8] = {p0.x, p0.y, p0.z, p0.w, p1.x, p1.y, p1.z, p1.w};
  float s = 0.f;
  #pragma unroll
  for (int e = 0; e < 8; ++e) { float d = pv[e] - c[e]; s += d * d; }
  #pragma unroll
  for (int o = 32; o > 0; o >>= 1) s += __shfl_down(s, o, 64);
  __shared__ float red[4];
  if ((tid & 63) == 0) red[tid >> 6] = s;
  __syncthreads();
  if (tid == 0) strp[blockIdx.x] = red[0] + red[1] + red[2] + red[3];
}

// ---------- final: fp64 reduce of partials, combine losses ----------
__global__ __launch_bounds__(256)
void finalize_kernel(const float* __restrict__ cohp,
                     const float* __restrict__ wtp,
                     const float* __restrict__ strp,
                     float* __restrict__ out) {
  const int tid = threadIdx.x;
  double sc = 0, sw = 0, ss = 0;
  for (int i = tid; i < 2080; i += 256) sc += (double)cohp[i];
  for (int i = tid; i < 128;  i += 256) sw += (double)wtp[i];
  for (int i = tid; i < 512;  i += 256) ss += (double)strp[i];
  #pragma unroll
  for (int o = 32; o > 0; o >>= 1) {
    sc += __shfl_down(sc, o, 64);
    sw += __shfl_down(sw, o, 64);
    ss += __shfl_down(ss, o, 64);
  }
  __shared__ double rd[3][4];
  const int w = tid >> 6, lane = tid & 63;
  if (lane == 0) { rd[0][w] = sc; rd[1][w] = sw; rd[2][w] = ss; }
  __syncthreads();
  if (tid == 0) {
    double c  = rd[0][0] + rd[0][1] + rd[0][2] + rd[0][3];
    double wv = rd[1][0] + rd[1][1] + rd[1][2] + rd[1][3];
    double st = rd[2][0] + rd[2][1] + rd[2][2] + rd[2][3];
    out[0] = (float)(c / ((double)N * (double)N) +
                     st / ((double)N * (double)P) +
                     wv / ((double)N * (double)P));
  }
}

extern "C" void kernel_launch(void* const* d_in, const int* in_sizes, int n_in,
                              void* d_out, int out_size, void* d_ws, size_t ws_size,
                              hipStream_t stream) {
  const float* pred = (const float*)d_in[0];   // [8192,128]
  const float* emb  = (const float*)d_in[1];   // [8192,256]
  const float* adj  = (const float*)d_in[2];   // [8192,8192]
  const float* wts  = (const float*)d_in[3];   // [8192,128]
  float* out = (float*)d_out;
  char* ws = (char*)d_ws;
  // ws layout (~18.9 MB):
  //   [0, 12.58 MB): a_cat+b_cat during prep+coherence; then OVERLAID by cpart
  //   cpart (bf16 partial C, 8 x 8192x128) = [0, 16 MB)  -- written after coherence reads cats
  unsigned short* a_cat = (unsigned short*)ws;               // [8192,384] bf16
  unsigned short* b_cat = (unsigned short*)(ws + 6291456);   // [8192,384] bf16
  unsigned short* cpart = (unsigned short*)ws;               // 8 x [8192,128] bf16 = 16 MB
  unsigned short* predT = (unsigned short*)(ws + 16777216);  // [128,8192] bf16 = 2 MB
  float* cohp = (float*)(ws + 18874368);                     // 2080
  float* wtp  = cohp + 2080;                                 // 128
  float* strp = wtp + 128;                                   // 512

  prep_xn_kernel  <<<N,          256, 0, stream>>>(emb, a_cat, b_cat);
  prep_pred_kernel<<<N / 64,     256, 0, stream>>>(pred, wts, a_cat, b_cat, predT, wtp);
  coherence_kernel<<<2080,       256, 0, stream>>>(a_cat, b_cat, cohp);
  structure_mfma_kernel<<<dim3(128, 8), 256, 0, stream>>>(adj, predT, cpart);
  structure_reduce_kernel<<<512, 256, 0, stream>>>(cpart, pred, strp);
  finalize_kernel <<<1,          256, 0, stream>>>(cohp, wtp, strp, out);
}

// Round 3
// 494.018 us; speedup vs baseline: 1.1976x; 1.0956x over previous
//
#include <hip/hip_runtime.h>

#define AS1 __attribute__((address_space(1)))
#define AS3 __attribute__((address_space(3)))

typedef __attribute__((ext_vector_type(8))) __bf16 bf16x8;
typedef __attribute__((ext_vector_type(8))) unsigned short ushort8;
typedef __attribute__((ext_vector_type(4))) float f32x4;

static constexpr int N  = 8192;
static constexpr int P  = 128;
static constexpr int D  = 256;
static constexpr int KC = 384;   // P + D concatenated K

__device__ __forceinline__ unsigned short f32_bf16(float f) {
  union { float f; unsigned u; } v; v.f = f;
  unsigned r = v.u + 0x7fffu + ((v.u >> 16) & 1u);   // round-to-nearest-even
  return (unsigned short)(r >> 16);
}

__device__ __forceinline__ void glds16(const void* g, void* l) {
  __builtin_amdgcn_global_load_lds((const AS1 void*)g, (AS3 void*)l, 16, 0, 0);
}

// ---------- P1: row-normalize embeddings -> xn into a_cat, -xn into b_cat ----------
__global__ __launch_bounds__(256)
void prep_xn_kernel(const float* __restrict__ emb,
                    unsigned short* __restrict__ a_cat,
                    unsigned short* __restrict__ b_cat) {
  const int i = blockIdx.x;
  const int j = threadIdx.x;            // D == 256 == blockDim
  float x = emb[(size_t)i * D + j];
  float ss = x * x;
  #pragma unroll
  for (int o = 32; o > 0; o >>= 1) ss += __shfl_down(ss, o, 64);
  __shared__ float red[4];
  if ((threadIdx.x & 63) == 0) red[threadIdx.x >> 6] = ss;
  __syncthreads();
  float tot = red[0] + red[1] + red[2] + red[3];
  float inv = 1.0f / fmaxf(sqrtf(tot), 1e-8f);
  float xn = x * inv;
  a_cat[(size_t)i * KC + P + j] = f32_bf16(xn);
  b_cat[(size_t)i * KC + P + j] = f32_bf16(-xn);
}

// ---------- P2: cast Pred -> cat arrays + LDS-tiled transpose predT + weight loss ----------
__global__ __launch_bounds__(256)
void prep_pred_kernel(const float* __restrict__ pred,
                      const float* __restrict__ wts,
                      unsigned short* __restrict__ a_cat,
                      unsigned short* __restrict__ b_cat,
                      unsigned short* __restrict__ predT,
                      float* __restrict__ wtp) {
  __shared__ unsigned short t[P][72];   // 64 i-cols + pad
  const int tid = threadIdx.x;
  const int i0 = blockIdx.x * 64;
  float s = 0.f;
  #pragma unroll
  for (int k = 0; k < 32; ++k) {
    int e = k * 256 + tid;              // 0..8191 over 64x128 tile
    int ii = e >> 7, p = e & 127;
    size_t idx = (size_t)(i0 + ii) * P + p;
    float v = pred[idx];
    unsigned short h = f32_bf16(v);
    a_cat[(size_t)(i0 + ii) * KC + p] = h;
    b_cat[(size_t)(i0 + ii) * KC + p] = h;
    t[p][ii] = h;
    float d = v - wts[idx];
    s += d * d;
  }
  __syncthreads();
  #pragma unroll
  for (int k = 0; k < 32; ++k) {
    int e = k * 256 + tid;
    int p = e >> 6, ii = e & 63;
    predT[(size_t)p * N + i0 + ii] = t[p][ii];   // coalesced 128B runs
  }
  #pragma unroll
  for (int o = 32; o > 0; o >>= 1) s += __shfl_down(s, o, 64);
  __shared__ float red[4];
  if ((tid & 63) == 0) red[tid >> 6] = s;
  __syncthreads();
  if (tid == 0) wtp[blockIdx.x] = red[0] + red[1] + red[2] + red[3];
}

// ---------- coherence: 128x256 tiles, triangular grid, per-element sym weights ----------
__global__ __launch_bounds__(256, 2)
void coherence_kernel(const unsigned short* __restrict__ A,
                      const unsigned short* __restrict__ B,
                      float* __restrict__ cohp) {
  const int t = blockIdx.x;             // 0..1055; offset(bj) = bj^2 + bj
  int bj = (int)((sqrtf(4.0f * (float)t + 1.0f) - 1.0f) * 0.5f);
  while ((bj + 1) * (bj + 2) <= t) ++bj;      // (bj+1)^2+(bj+1) <= t
  while (bj * bj + bj > t) --bj;
  const int bi = t - bj * bj - bj;            // bi in [0, 2*bj+2)
  const int tid = threadIdx.x;
  __shared__ unsigned short As[128 * 32];     // 8 KB
  __shared__ unsigned short Bs[256 * 32];     // 16 KB
  const int w = tid >> 6, lane = tid & 63;
  const int wr = (w & 1) * 64, wc = (w >> 1) * 128;
  const int ml = lane & 15, kq = (lane >> 4) * 8;
  f32x4 acc[4][8] = {};
  const size_t abase = (size_t)bi * 128 * KC;
  const size_t bbase = (size_t)bj * 256 * KC;
  for (int k0 = 0; k0 < KC; k0 += 32) {
    __syncthreads();
    #pragma unroll
    for (int p = 0; p < 2; ++p) {           // A: 8 KB
      int e = p * 2048 + tid * 8;
      int row = e >> 5, col = e & 31;
      glds16(A + abase + (size_t)row * KC + k0 + col, &As[e]);
    }
    #pragma unroll
    for (int p = 0; p < 4; ++p) {           // B: 16 KB
      int e = p * 2048 + tid * 8;
      int row = e >> 5, col = e & 31;
      glds16(B + bbase + (size_t)row * KC + k0 + col, &Bs[e]);
    }
    __syncthreads();
    bf16x8 af[4], bf[8];
    #pragma unroll
    for (int a = 0; a < 4; ++a) af[a] = *(const bf16x8*)&As[(wr + a * 16 + ml) * 32 + kq];
    #pragma unroll
    for (int f = 0; f < 8; ++f) bf[f] = *(const bf16x8*)&Bs[(wc + f * 16 + ml) * 32 + kq];
    #pragma unroll
    for (int a = 0; a < 4; ++a)
      #pragma unroll
      for (int f = 0; f < 8; ++f)
        acc[a][f] = __builtin_amdgcn_mfma_f32_16x16x32_bf16(af[a], bf[f], acc[a][f], 0, 0, 0);
  }
  // C/D: col=lane&15 (B/j index), row=(lane>>4)*4+e (A/i index)  [m89/m91]
  float s = 0.f;
  const int ib = bi * 128 + wr + (lane >> 4) * 4;
  const int jb = bj * 256 + wc + ml;
  #pragma unroll
  for (int a = 0; a < 4; ++a)
    #pragma unroll
    for (int f = 0; f < 8; ++f)
      #pragma unroll
      for (int e = 0; e < 4; ++e) {
        int i = ib + a * 16 + e, j = jb + f * 16;
        float wgt = (i < j) ? 2.f : ((i == j) ? 1.f : 0.f);
        float c = acc[a][f][e];
        s += wgt * c * c;
      }
  #pragma unroll
  for (int o = 32; o > 0; o >>= 1) s += __shfl_down(s, o, 64);
  __shared__ float red[4];
  if (lane == 0) red[w] = s;
  __syncthreads();
  if (tid == 0) cohp[t] = red[0] + red[1] + red[2] + red[3];
}

// ---------- structure v3: B once-per-round in LDS (lgkmcnt), adj-only vmcnt stream ----------
// grid (128 row-blocks, 4 k-slices); block = 4 waves x 16 rows; 8 rounds x 256k per block.
__global__ __launch_bounds__(256, 2)
void structure_mfma_kernel(const float* __restrict__ adj,
                           const unsigned short* __restrict__ predT,
                           float* __restrict__ cpart) {
  __shared__ unsigned short Bs[8 * 128 * 32];   // [chunk][p][32k] bf16 = 64 KB
  const int tid = threadIdx.x;
  const int w = tid >> 6, lane = tid & 63;
  const int ml = lane & 15, kq = (lane >> 4) * 8;
  const int row0 = blockIdx.x * 64 + w * 16;
  const int slice = blockIdx.y;                 // 0..3
  f32x4 acc[8] = {};

  for (int r = 0; r < 8; ++r) {
    const int kbase = (r * 4 + slice) * 256;
    if (r) __syncthreads();                     // all waves done reading Bs
    // stage B: predT[p][kbase..kbase+255] -> Bs[c][p][kk], coalesced 16B/lane reads
    #pragma unroll
    for (int i = 0; i < 16; ++i) {
      int e = i * 256 + tid;                    // 4096 ushort8 groups
      int p = e >> 5, kg = e & 31;
      ushort8 v = *(const ushort8*)(predT + (size_t)p * N + kbase + kg * 8);
      int c = kg >> 2, kk = (kg & 3) * 8;
      *(ushort8*)&Bs[(c * 128 + p) * 32 + kk] = v;
    }
    __syncthreads();

    const float* abase = adj + (size_t)(row0 + ml) * N + kbase + kq;
    float4 ring[3][2];
    #pragma unroll
    for (int s = 0; s < 3; ++s) {
      ring[s][0] = *(const float4*)(abase + s * 32);
      ring[s][1] = *(const float4*)(abase + s * 32 + 4);
    }
    #pragma unroll
    for (int c = 0; c < 8; ++c) {
      float4 a0 = ring[c % 3][0], a1 = ring[c % 3][1];
      if (c < 5) {
        ring[c % 3][0] = *(const float4*)(abase + (c + 3) * 32);
        ring[c % 3][1] = *(const float4*)(abase + (c + 3) * 32 + 4);
      }
      union { bf16x8 v; unsigned short s[8]; } ah;
      ah.s[0] = f32_bf16(a0.x); ah.s[1] = f32_bf16(a0.y);
      ah.s[2] = f32_bf16(a0.z); ah.s[3] = f32_bf16(a0.w);
      ah.s[4] = f32_bf16(a1.x); ah.s[5] = f32_bf16(a1.y);
      ah.s[6] = f32_bf16(a1.z); ah.s[7] = f32_bf16(a1.w);
      #pragma unroll
      for (int f = 0; f < 8; ++f) {
        bf16x8 bf = *(const bf16x8*)&Bs[(c * 128 + f * 16 + ml) * 32 + kq];
        acc[f] = __builtin_amdgcn_mfma_f32_16x16x32_bf16(ah.v, bf, acc[f], 0, 0, 0);
      }
    }
  }
  // epilogue: fp32 partial, 64-B full-granule runs
  float* cp = cpart + (size_t)slice * ((size_t)N * P);
  const int rb = row0 + (lane >> 4) * 4;
  #pragma unroll
  for (int f = 0; f < 8; ++f)
    #pragma unroll
    for (int e = 0; e < 4; ++e)
      cp[(size_t)(rb + e) * P + f * 16 + ml] = acc[f][e];
}

// ---------- structure reduce: sum 4 fp32 partial slices, (pred - C)^2 ----------
__global__ __launch_bounds__(256)
void structure_reduce_kernel(const float* __restrict__ cpart,
                             const float* __restrict__ pred,
                             float* __restrict__ strp) {
  const int tid = threadIdx.x;
  const size_t base = ((size_t)blockIdx.x * 256 + tid) * 8;
  const float4 p0 = *(const float4*)(pred + base);
  const float4 p1 = *(const float4*)(pred + base + 4);
  float c[8] = {};
  #pragma unroll
  for (int sl = 0; sl < 4; ++sl) {
    float4 c0 = *(const float4*)(cpart + (size_t)sl * ((size_t)N * P) + base);
    float4 c1 = *(const float4*)(cpart + (size_t)sl * ((size_t)N * P) + base + 4);
    c[0] += c0.x; c[1] += c0.y; c[2] += c0.z; c[3] += c0.w;
    c[4] += c1.x; c[5] += c1.y; c[6] += c1.z; c[7] += c1.w;
  }
  const float pv[8] = {p0.x, p0.y, p0.z, p0.w, p1.x, p1.y, p1.z, p1.w};
  float s = 0.f;
  #pragma unroll
  for (int e = 0; e < 8; ++e) { float d = pv[e] - c[e]; s += d * d; }
  #pragma unroll
  for (int o = 32; o > 0; o >>= 1) s += __shfl_down(s, o, 64);
  __shared__ float red[4];
  if ((tid & 63) == 0) red[tid >> 6] = s;
  __syncthreads();
  if (tid == 0) strp[blockIdx.x] = red[0] + red[1] + red[2] + red[3];
}

// ---------- final: fp64 reduce of partials, combine losses ----------
__global__ __launch_bounds__(256)
void finalize_kernel(const float* __restrict__ cohp,
                     const float* __restrict__ wtp,
                     const float* __restrict__ strp,
                     float* __restrict__ out) {
  const int tid = threadIdx.x;
  double sc = 0, sw = 0, ss = 0;
  for (int i = tid; i < 1056; i += 256) sc += (double)cohp[i];
  for (int i = tid; i < 128;  i += 256) sw += (double)wtp[i];
  for (int i = tid; i < 512;  i += 256) ss += (double)strp[i];
  #pragma unroll
  for (int o = 32; o > 0; o >>= 1) {
    sc += __shfl_down(sc, o, 64);
    sw += __shfl_down(sw, o, 64);
    ss += __shfl_down(ss, o, 64);
  }
  __shared__ double rd[3][4];
  const int w = tid >> 6, lane = tid & 63;
  if (lane == 0) { rd[0][w] = sc; rd[1][w] = sw; rd[2][w] = ss; }
  __syncthreads();
  if (tid == 0) {
    double c  = rd[0][0] + rd[0][1] + rd[0][2] + rd[0][3];
    double wv = rd[1][0] + rd[1][1] + rd[1][2] + rd[1][3];
    double st = rd[2][0] + rd[2][1] + rd[2][2] + rd[2][3];
    out[0] = (float)(c / ((double)N * (double)N) +
                     st / ((double)N * (double)P) +
                     wv / ((double)N * (double)P));
  }
}

extern "C" void kernel_launch(void* const* d_in, const int* in_sizes, int n_in,
                              void* d_out, int out_size, void* d_ws, size_t ws_size,
                              hipStream_t stream) {
  const float* pred = (const float*)d_in[0];   // [8192,128]
  const float* emb  = (const float*)d_in[1];   // [8192,256]
  const float* adj  = (const float*)d_in[2];   // [8192,8192]
  const float* wts  = (const float*)d_in[3];   // [8192,128]
  float* out = (float*)d_out;
  char* ws = (char*)d_ws;
  // ws (~18.9 MB): [0,16MB) cpart (4 fp32 slices) OVERLAYS a_cat+b_cat (12.6MB,
  // dead after coherence, which precedes structure in stream order).
  unsigned short* a_cat = (unsigned short*)ws;               // [8192,384] bf16
  unsigned short* b_cat = (unsigned short*)(ws + 6291456);   // [8192,384] bf16
  float*          cpart = (float*)ws;                        // 4 x [8192,128] fp32 = 16 MB
  unsigned short* predT = (unsigned short*)(ws + 16777216);  // [128,8192] bf16 = 2 MB
  float* cohp = (float*)(ws + 18874368);                     // 1056
  float* wtp  = cohp + 1056;                                 // 128
  float* strp = wtp + 128;                                   // 512

  prep_xn_kernel  <<<N,          256, 0, stream>>>(emb, a_cat, b_cat);
  prep_pred_kernel<<<N / 64,     256, 0, stream>>>(pred, wts, a_cat, b_cat, predT, wtp);
  coherence_kernel<<<1056,       256, 0, stream>>>(a_cat, b_cat, cohp);
  structure_mfma_kernel<<<dim3(128, 4), 256, 0, stream>>>(adj, predT, cpart);
  structure_reduce_kernel<<<512, 256, 0, stream>>>(cpart, pred, strp);
  finalize_kernel <<<1,          256, 0, stream>>>(cohp, wtp, strp, out);
}